// Round 4
// baseline (665.124 us; speedup 1.0000x reference)
//
#include <hip/hip_runtime.h>
#include <hip/hip_bf16.h>

typedef __attribute__((ext_vector_type(8))) short short8;
typedef __attribute__((ext_vector_type(4))) float f32x4;
typedef __attribute__((ext_vector_type(4))) int int4v;

#define CAPB 384   // per-bin capacity (mean 244, sigma ~15.6 -> 9 sigma)

__device__ inline unsigned short f2bf(float f) {   // RNE, used in one-time swizzle only
  unsigned u = __float_as_uint(f);
  return (unsigned short)((u + 0x7FFFu + ((u >> 16) & 1u)) >> 16);
}
__device__ inline short bfc(float f) {             // hot path: compiler lowers to v_cvt_pk
  __hip_bfloat16 h = __float2bfloat16(f);
  return *(short*)&h;
}
__device__ inline __attribute__((always_inline))
f32x4 mfma16(short8 a, short8 b, f32x4 c) {
  return __builtin_amdgcn_mfma_f32_16x16x32_bf16(a, b, c, 0, 0, 0);
}

// ---------------- kernel A: bin items into d_ws buckets ----------------
__global__ __launch_bounds__(256)
void bin_items(const int* __restrict__ idxs, int* __restrict__ wsCnt,
               int* __restrict__ wsIds, int n_items)
{
  const int i0 = blockIdx.x * blockDim.x + threadIdx.x;
  const int stride = gridDim.x * blockDim.x;
  const int nq = n_items >> 2;
  const int4v* idx4 = (const int4v*)idxs;
  for (int s = i0; s < nq; s += stride) {
    int4v v = idx4[s];
    #pragma unroll
    for (int e = 0; e < 4; ++e) {
      int bin = v[e];
      int pos = atomicAdd(&wsCnt[bin], 1);
      if (pos < CAPB) wsIds[bin * CAPB + pos] = s * 4 + e;
    }
  }
  for (int i = (nq << 2) + i0; i < n_items; i += stride) {
    int bin = idxs[i];
    int pos = atomicAdd(&wsCnt[bin], 1);
    if (pos < CAPB) wsIds[bin * CAPB + pos] = i;
  }
}

// ---------------- kernel B: per-bin MLP h-sums + GEMM2 ----------------
// LDS: sW1 32768B | sW2 65536B | sB1 1024B | sB2 512B | sHs 8448B = 108288B
#define LDS_BYTES 108288

__global__ __launch_bounds__(512, 2)
void mlp_bin3(const float* __restrict__ x,
              const float* __restrict__ W1,
              const float* __restrict__ b1,
              const float* __restrict__ W2,
              const float* __restrict__ b2,
              const int* __restrict__ wsCnt,
              const int* __restrict__ wsIds,
              float* __restrict__ out)
{
  extern __shared__ char smem[];
  unsigned short* sW1 = (unsigned short*)smem;            // 16384
  unsigned short* sW2 = sW1 + 16384;                      // 32768
  float* sB1 = (float*)(smem + 98304);                    // 256
  float* sB2 = (float*)(smem + 99328);                    // 128
  unsigned short* sHs = (unsigned short*)(smem + 99840);  // 16*264

  const int tid = threadIdx.x;
  const int myblk = blockIdx.x;

  // ---- weight swizzle f32 -> bf16 MFMA fragments (layout verified r1-r3) ----
  for (int f = tid; f < 16384; f += 512) {
    int blk = f >> 9;                 // mt*2+kt
    int mt = blk >> 1, kt = blk & 1;
    int ln = (f >> 3) & 63, j = f & 7;
    int qq = ln >> 4, cc = ln & 15;
    sW1[f] = f2bf(W1[(32*kt + 8*qq + j)*256 + 16*mt + cc]);
  }
  for (int f = tid; f < 32768; f += 512) {
    int blk = f >> 9;                 // mt2*8+kt2
    int mt2 = blk >> 3, kt2 = blk & 7;
    int ln = (f >> 3) & 63, j = f & 7;
    int qq = ln >> 4, cc = ln & 15;
    sW2[f] = f2bf(W2[(32*kt2 + 8*qq + j)*128 + 16*mt2 + cc]);
  }
  if (tid < 256) sB1[tid] = b1[tid];
  if (tid < 128) sB2[tid] = b2[tid];
  __syncthreads();

  const int lane = tid & 63;
  const int wave = tid >> 6;
  const int c = lane & 15;
  const int q = lane >> 4;

  // ---- each wave owns 2 bins; accumulate sum of relu(W1^T x + b1) in regs ----
  #pragma unroll 1
  for (int bsel = 0; bsel < 2; ++bsel) {
    const int lb = wave * 2 + bsel;
    const int gbin = myblk * 16 + lb;
    const int cnt = min(wsCnt[gbin], CAPB);
    const int passes = (cnt + 63) >> 6;          // 64 items per pass (G=4 groups)
    const int* ids = wsIds + gbin * CAPB;

    float hsum[8][8];   // [kt2][half*4+r]
    #pragma unroll
    for (int a = 0; a < 8; ++a)
      #pragma unroll
      for (int bq = 0; bq < 8; ++bq) hsum[a][bq] = 0.f;

    f32x4 xr[16];       // raw f32 prefetch for next pass (4 groups x 4 vecs)
    short8 xf[4][2];    // current pass bf16 fragments

    // prologue: gather + convert pass 0
    if (passes > 0) {
      #pragma unroll
      for (int gi = 0; gi < 4; ++gi) {
        int slot = gi*16 + c;
        int id = ids[min(slot, cnt - 1)];
        const float* xp = x + (long)id * 64 + 8*q;
        xr[gi*4+0] = *(const f32x4*)(xp);
        xr[gi*4+1] = *(const f32x4*)(xp + 4);
        xr[gi*4+2] = *(const f32x4*)(xp + 32);
        xr[gi*4+3] = *(const f32x4*)(xp + 36);
      }
      #pragma unroll
      for (int gi = 0; gi < 4; ++gi) {
        bool v = (gi*16 + c) < cnt;
        f32x4 a0 = xr[gi*4+0], a1 = xr[gi*4+1], a2 = xr[gi*4+2], a3 = xr[gi*4+3];
        short8 f0, f1;
        f0[0]=bfc(a0[0]); f0[1]=bfc(a0[1]); f0[2]=bfc(a0[2]); f0[3]=bfc(a0[3]);
        f0[4]=bfc(a1[0]); f0[5]=bfc(a1[1]); f0[6]=bfc(a1[2]); f0[7]=bfc(a1[3]);
        f1[0]=bfc(a2[0]); f1[1]=bfc(a2[1]); f1[2]=bfc(a2[2]); f1[3]=bfc(a2[3]);
        f1[4]=bfc(a3[0]); f1[5]=bfc(a3[1]); f1[6]=bfc(a3[2]); f1[7]=bfc(a3[3]);
        short8 z = {0,0,0,0,0,0,0,0};
        xf[gi][0] = v ? f0 : z;
        xf[gi][1] = v ? f1 : z;
      }
    }

    for (int p = 0; p < passes; ++p) {
      // issue next pass's gather early (hidden under MFMA sweep)
      if (p + 1 < passes) {
        #pragma unroll
        for (int gi = 0; gi < 4; ++gi) {
          int slot = (p+1)*64 + gi*16 + c;
          int id = ids[min(slot, cnt - 1)];
          const float* xp = x + (long)id * 64 + 8*q;
          xr[gi*4+0] = *(const f32x4*)(xp);
          xr[gi*4+1] = *(const f32x4*)(xp + 4);
          xr[gi*4+2] = *(const f32x4*)(xp + 32);
          xr[gi*4+3] = *(const f32x4*)(xp + 36);
        }
      }

      // GEMM1 sweep: 16 weight tiles x 4 item-groups, relu-accumulate
      #pragma unroll
      for (int kt2 = 0; kt2 < 8; ++kt2) {
        #pragma unroll
        for (int half = 0; half < 2; ++half) {
          const int mt = 2*kt2 + half;
          f32x4 bias = *(const f32x4*)(sB1 + 16*mt + 4*q);
          f32x4 g1v[4];
          #pragma unroll
          for (int gi = 0; gi < 4; ++gi) g1v[gi] = bias;
          short8 w0 = *(const short8*)(sW1 + (mt*2 + 0)*512 + lane*8);
          #pragma unroll
          for (int gi = 0; gi < 4; ++gi) g1v[gi] = mfma16(w0, xf[gi][0], g1v[gi]);
          short8 w1 = *(const short8*)(sW1 + (mt*2 + 1)*512 + lane*8);
          #pragma unroll
          for (int gi = 0; gi < 4; ++gi) g1v[gi] = mfma16(w1, xf[gi][1], g1v[gi]);
          #pragma unroll
          for (int gi = 0; gi < 4; ++gi)
            #pragma unroll
            for (int r = 0; r < 4; ++r)
              hsum[kt2][half*4 + r] += fmaxf(g1v[gi][r], 0.f);
        }
      }

      // convert next pass (compiler inserts waitcnt on xr here)
      if (p + 1 < passes) {
        #pragma unroll
        for (int gi = 0; gi < 4; ++gi) {
          bool v = ((p+1)*64 + gi*16 + c) < cnt;
          f32x4 a0 = xr[gi*4+0], a1 = xr[gi*4+1], a2 = xr[gi*4+2], a3 = xr[gi*4+3];
          short8 f0, f1;
          f0[0]=bfc(a0[0]); f0[1]=bfc(a0[1]); f0[2]=bfc(a0[2]); f0[3]=bfc(a0[3]);
          f0[4]=bfc(a1[0]); f0[5]=bfc(a1[1]); f0[6]=bfc(a1[2]); f0[7]=bfc(a1[3]);
          f1[0]=bfc(a2[0]); f1[1]=bfc(a2[1]); f1[2]=bfc(a2[2]); f1[3]=bfc(a2[3]);
          f1[4]=bfc(a3[0]); f1[5]=bfc(a3[1]); f1[6]=bfc(a3[2]); f1[7]=bfc(a3[3]);
          short8 z = {0,0,0,0,0,0,0,0};
          xf[gi][0] = v ? f0 : z;
          xf[gi][1] = v ? f1 : z;
        }
      }
    }

    // padded items contributed exactly relu(b1) each -> subtract (wave-uniform n)
    const int n_inv = passes*64 - cnt;
    if (n_inv > 0) {
      const float fn = (float)n_inv;
      #pragma unroll
      for (int kt2 = 0; kt2 < 8; ++kt2)
        #pragma unroll
        for (int half = 0; half < 2; ++half)
          #pragma unroll
          for (int r = 0; r < 4; ++r)
            hsum[kt2][half*4 + r] -= fn * fmaxf(sB1[16*(2*kt2+half) + 4*q + r], 0.f);
    }

    // cross-lane reduce over the 16 item-columns (lane bits 0-3)
    #pragma unroll
    for (int a = 0; a < 8; ++a)
      #pragma unroll
      for (int bq = 0; bq < 8; ++bq) {
        float v = hsum[a][bq];
        v += __shfl_xor(v, 1);
        v += __shfl_xor(v, 2);
        v += __shfl_xor(v, 4);
        v += __shfl_xor(v, 8);
        hsum[a][bq] = v;
      }

    // stage bin h-sum as bf16 (c==0 lanes; q covers the 4q+r rows)
    if (c == 0) {
      #pragma unroll
      for (int kt2 = 0; kt2 < 8; ++kt2)
        #pragma unroll
        for (int half = 0; half < 2; ++half) {
          unsigned d0 = (unsigned)f2bf(hsum[kt2][half*4+0]) | ((unsigned)f2bf(hsum[kt2][half*4+1]) << 16);
          unsigned d1 = (unsigned)f2bf(hsum[kt2][half*4+2]) | ((unsigned)f2bf(hsum[kt2][half*4+3]) << 16);
          unsigned* dst = (unsigned*)(sHs + lb*264 + kt2*32 + half*16 + 4*q);
          dst[0] = d0; dst[1] = d1;
        }
    }
  }
  __syncthreads();

  // ---- GEMM2 once per bin: out[bin] = W2^T @ hsum[bin] + cnt*b2 ----
  {
    const int mt2 = wave;   // 8 waves x 16 feats = 128 feats
    f32x4 acc = {0.f, 0.f, 0.f, 0.f};
    #pragma unroll
    for (int kt2 = 0; kt2 < 8; ++kt2) {
      short8 w2 = *(const short8*)(sW2 + (mt2*8 + kt2)*512 + lane*8);
      short8 hf = *(const short8*)(sHs + c*264 + kt2*32 + 8*q);
      acc = mfma16(w2, hf, acc);
    }
    const int cntc = min(wsCnt[myblk*16 + c], CAPB);
    f32x4 res;
    #pragma unroll
    for (int r = 0; r < 4; ++r)
      res[r] = acc[r] + (float)cntc * sB2[16*mt2 + 4*q + r];
    float* op = out + ((long)myblk*16 + c)*128 + 16*mt2 + 4*q;
    *(f32x4*)op = res;
  }
}

extern "C" void kernel_launch(void* const* d_in, const int* in_sizes, int n_in,
                              void* d_out, int out_size, void* d_ws, size_t ws_size,
                              hipStream_t stream) {
  const float* x  = (const float*)d_in[0];
  const int* idxs = (const int*)d_in[1];
  // d_in[2] = n_bins scalar
  const float* W1 = (const float*)d_in[3];
  const float* b1 = (const float*)d_in[4];
  const float* W2 = (const float*)d_in[5];
  const float* b2 = (const float*)d_in[6];
  float* out = (float*)d_out;
  const int n_items = in_sizes[1];
  const int n_bins = out_size / 128;            // 4096
  const int nblocks = n_bins / 16;              // 256

  int* wsCnt = (int*)d_ws;                      // 4096 ints
  int* wsIds = (int*)d_ws + 4096;               // 4096 * CAPB ints (~6.3 MB)

  hipMemsetAsync(wsCnt, 0, (size_t)n_bins * sizeof(int), stream);
  bin_items<<<1024, 256, 0, stream>>>(idxs, wsCnt, wsIds, n_items);
  mlp_bin3<<<nblocks, 512, LDS_BYTES, stream>>>(x, W1, b1, W2, b2, wsCnt, wsIds, out);
}

// Round 5
// 660.142 us; speedup vs baseline: 1.0075x; 1.0075x over previous
//
#include <hip/hip_runtime.h>
#include <hip/hip_bf16.h>

typedef __attribute__((ext_vector_type(8))) short short8;
typedef __attribute__((ext_vector_type(4))) float f32x4;
typedef __attribute__((ext_vector_type(4))) int int4v;

#define CAPB 384   // per-bin capacity (mean 244, sigma ~15.6 -> 9 sigma)

__device__ inline unsigned short f2bf(float f) {   // RNE, used in one-time swizzle only
  unsigned u = __float_as_uint(f);
  return (unsigned short)((u + 0x7FFFu + ((u >> 16) & 1u)) >> 16);
}
__device__ inline short bfc(float f) {             // hot path: compiler lowers to v_cvt_pk
  __hip_bfloat16 h = __float2bfloat16(f);
  return *(short*)&h;
}
__device__ inline __attribute__((always_inline))
f32x4 mfma16(short8 a, short8 b, f32x4 c) {
  return __builtin_amdgcn_mfma_f32_16x16x32_bf16(a, b, c, 0, 0, 0);
}

// ---------------- kernel A: bin items into d_ws buckets ----------------
__global__ __launch_bounds__(256)
void bin_items(const int* __restrict__ idxs, int* __restrict__ wsCnt,
               int* __restrict__ wsIds, int n_items)
{
  const int i0 = blockIdx.x * blockDim.x + threadIdx.x;
  const int stride = gridDim.x * blockDim.x;
  const int nq = n_items >> 2;
  const int4v* idx4 = (const int4v*)idxs;
  for (int s = i0; s < nq; s += stride) {
    int4v v = idx4[s];
    #pragma unroll
    for (int e = 0; e < 4; ++e) {
      int bin = v[e];
      int pos = atomicAdd(&wsCnt[bin], 1);
      if (pos < CAPB) wsIds[bin * CAPB + pos] = s * 4 + e;
    }
  }
  for (int i = (nq << 2) + i0; i < n_items; i += stride) {
    int bin = idxs[i];
    int pos = atomicAdd(&wsCnt[bin], 1);
    if (pos < CAPB) wsIds[bin * CAPB + pos] = i;
  }
}

// ---------------- kernel B: per-bin MLP h-sums + GEMM2 ----------------
// LDS: sW1 32768B | sW2 65536B | sB1 1024B | sB2 512B | sHs 8448B = 108288B
#define LDS_BYTES 108288

// NOTE: __launch_bounds__(512) ONLY — a min-waves/EU of 2 caps VGPR at 128
// and spilled ~60 regs/lane -> 1 GB scratch traffic in round 4.
__global__ __launch_bounds__(512)
void mlp_bin3(const float* __restrict__ x,
              const float* __restrict__ W1,
              const float* __restrict__ b1,
              const float* __restrict__ W2,
              const float* __restrict__ b2,
              const int* __restrict__ wsCnt,
              const int* __restrict__ wsIds,
              float* __restrict__ out)
{
  extern __shared__ char smem[];
  unsigned short* sW1 = (unsigned short*)smem;            // 16384
  unsigned short* sW2 = sW1 + 16384;                      // 32768
  float* sB1 = (float*)(smem + 98304);                    // 256
  float* sB2 = (float*)(smem + 99328);                    // 128
  unsigned short* sHs = (unsigned short*)(smem + 99840);  // 16*264

  const int tid = threadIdx.x;
  const int myblk = blockIdx.x;

  // ---- weight swizzle f32 -> bf16 MFMA fragments (layout verified r1-r4) ----
  for (int f = tid; f < 16384; f += 512) {
    int blk = f >> 9;                 // mt*2+kt
    int mt = blk >> 1, kt = blk & 1;
    int ln = (f >> 3) & 63, j = f & 7;
    int qq = ln >> 4, cc = ln & 15;
    sW1[f] = f2bf(W1[(32*kt + 8*qq + j)*256 + 16*mt + cc]);
  }
  for (int f = tid; f < 32768; f += 512) {
    int blk = f >> 9;                 // mt2*8+kt2
    int mt2 = blk >> 3, kt2 = blk & 7;
    int ln = (f >> 3) & 63, j = f & 7;
    int qq = ln >> 4, cc = ln & 15;
    sW2[f] = f2bf(W2[(32*kt2 + 8*qq + j)*128 + 16*mt2 + cc]);
  }
  if (tid < 256) sB1[tid] = b1[tid];
  if (tid < 128) sB2[tid] = b2[tid];
  __syncthreads();

  const int lane = tid & 63;
  const int wave = tid >> 6;
  const int c = lane & 15;
  const int q = lane >> 4;

  // ---- each wave owns 2 bins; accumulate sum of relu(W1^T x + b1) in regs ----
  #pragma unroll 1
  for (int bsel = 0; bsel < 2; ++bsel) {
    const int lb = wave * 2 + bsel;
    const int gbin = myblk * 16 + lb;
    const int cnt = min(wsCnt[gbin], CAPB);
    const int passes = (cnt + 63) >> 6;          // 64 items per pass (G=4 groups)
    const int* ids = wsIds + gbin * CAPB;

    float hsum[8][8];   // [kt2][half*4+r]
    #pragma unroll
    for (int a = 0; a < 8; ++a)
      #pragma unroll
      for (int bq = 0; bq < 8; ++bq) hsum[a][bq] = 0.f;

    f32x4 xr[16];       // raw f32 prefetch for next pass (4 groups x 4 vecs)
    short8 xf[4][2];    // current pass bf16 fragments

    // prologue: gather + convert pass 0
    if (passes > 0) {
      #pragma unroll
      for (int gi = 0; gi < 4; ++gi) {
        int slot = gi*16 + c;
        int id = ids[min(slot, cnt - 1)];
        const float* xp = x + (long)id * 64 + 8*q;
        xr[gi*4+0] = *(const f32x4*)(xp);
        xr[gi*4+1] = *(const f32x4*)(xp + 4);
        xr[gi*4+2] = *(const f32x4*)(xp + 32);
        xr[gi*4+3] = *(const f32x4*)(xp + 36);
      }
      #pragma unroll
      for (int gi = 0; gi < 4; ++gi) {
        bool v = (gi*16 + c) < cnt;
        f32x4 a0 = xr[gi*4+0], a1 = xr[gi*4+1], a2 = xr[gi*4+2], a3 = xr[gi*4+3];
        short8 f0, f1;
        f0[0]=bfc(a0[0]); f0[1]=bfc(a0[1]); f0[2]=bfc(a0[2]); f0[3]=bfc(a0[3]);
        f0[4]=bfc(a1[0]); f0[5]=bfc(a1[1]); f0[6]=bfc(a1[2]); f0[7]=bfc(a1[3]);
        f1[0]=bfc(a2[0]); f1[1]=bfc(a2[1]); f1[2]=bfc(a2[2]); f1[3]=bfc(a2[3]);
        f1[4]=bfc(a3[0]); f1[5]=bfc(a3[1]); f1[6]=bfc(a3[2]); f1[7]=bfc(a3[3]);
        short8 z = {0,0,0,0,0,0,0,0};
        xf[gi][0] = v ? f0 : z;
        xf[gi][1] = v ? f1 : z;
      }
    }

    for (int p = 0; p < passes; ++p) {
      // issue next pass's gather early (hidden under MFMA sweep)
      if (p + 1 < passes) {
        #pragma unroll
        for (int gi = 0; gi < 4; ++gi) {
          int slot = (p+1)*64 + gi*16 + c;
          int id = ids[min(slot, cnt - 1)];
          const float* xp = x + (long)id * 64 + 8*q;
          xr[gi*4+0] = *(const f32x4*)(xp);
          xr[gi*4+1] = *(const f32x4*)(xp + 4);
          xr[gi*4+2] = *(const f32x4*)(xp + 32);
          xr[gi*4+3] = *(const f32x4*)(xp + 36);
        }
      }

      // GEMM1 sweep: 16 weight tiles x 4 item-groups, relu-accumulate
      #pragma unroll
      for (int kt2 = 0; kt2 < 8; ++kt2) {
        #pragma unroll
        for (int half = 0; half < 2; ++half) {
          const int mt = 2*kt2 + half;
          f32x4 bias = *(const f32x4*)(sB1 + 16*mt + 4*q);
          f32x4 g1v[4];
          #pragma unroll
          for (int gi = 0; gi < 4; ++gi) g1v[gi] = bias;
          short8 w0 = *(const short8*)(sW1 + (mt*2 + 0)*512 + lane*8);
          #pragma unroll
          for (int gi = 0; gi < 4; ++gi) g1v[gi] = mfma16(w0, xf[gi][0], g1v[gi]);
          short8 w1 = *(const short8*)(sW1 + (mt*2 + 1)*512 + lane*8);
          #pragma unroll
          for (int gi = 0; gi < 4; ++gi) g1v[gi] = mfma16(w1, xf[gi][1], g1v[gi]);
          #pragma unroll
          for (int gi = 0; gi < 4; ++gi)
            #pragma unroll
            for (int r = 0; r < 4; ++r)
              hsum[kt2][half*4 + r] += fmaxf(g1v[gi][r], 0.f);
        }
      }

      // convert next pass (compiler inserts waitcnt on xr here)
      if (p + 1 < passes) {
        #pragma unroll
        for (int gi = 0; gi < 4; ++gi) {
          bool v = ((p+1)*64 + gi*16 + c) < cnt;
          f32x4 a0 = xr[gi*4+0], a1 = xr[gi*4+1], a2 = xr[gi*4+2], a3 = xr[gi*4+3];
          short8 f0, f1;
          f0[0]=bfc(a0[0]); f0[1]=bfc(a0[1]); f0[2]=bfc(a0[2]); f0[3]=bfc(a0[3]);
          f0[4]=bfc(a1[0]); f0[5]=bfc(a1[1]); f0[6]=bfc(a1[2]); f0[7]=bfc(a1[3]);
          f1[0]=bfc(a2[0]); f1[1]=bfc(a2[1]); f1[2]=bfc(a2[2]); f1[3]=bfc(a2[3]);
          f1[4]=bfc(a3[0]); f1[5]=bfc(a3[1]); f1[6]=bfc(a3[2]); f1[7]=bfc(a3[3]);
          short8 z = {0,0,0,0,0,0,0,0};
          xf[gi][0] = v ? f0 : z;
          xf[gi][1] = v ? f1 : z;
        }
      }
    }

    // padded items contributed exactly relu(b1) each -> subtract (wave-uniform n)
    const int n_inv = passes*64 - cnt;
    if (n_inv > 0) {
      const float fn = (float)n_inv;
      #pragma unroll
      for (int kt2 = 0; kt2 < 8; ++kt2)
        #pragma unroll
        for (int half = 0; half < 2; ++half)
          #pragma unroll
          for (int r = 0; r < 4; ++r)
            hsum[kt2][half*4 + r] -= fn * fmaxf(sB1[16*(2*kt2+half) + 4*q + r], 0.f);
    }

    // cross-lane reduce over the 16 item-columns (lane bits 0-3)
    #pragma unroll
    for (int a = 0; a < 8; ++a)
      #pragma unroll
      for (int bq = 0; bq < 8; ++bq) {
        float v = hsum[a][bq];
        v += __shfl_xor(v, 1);
        v += __shfl_xor(v, 2);
        v += __shfl_xor(v, 4);
        v += __shfl_xor(v, 8);
        hsum[a][bq] = v;
      }

    // stage bin h-sum as bf16 (c==0 lanes; q covers the 4q+r rows)
    if (c == 0) {
      #pragma unroll
      for (int kt2 = 0; kt2 < 8; ++kt2)
        #pragma unroll
        for (int half = 0; half < 2; ++half) {
          unsigned d0 = (unsigned)f2bf(hsum[kt2][half*4+0]) | ((unsigned)f2bf(hsum[kt2][half*4+1]) << 16);
          unsigned d1 = (unsigned)f2bf(hsum[kt2][half*4+2]) | ((unsigned)f2bf(hsum[kt2][half*4+3]) << 16);
          unsigned* dst = (unsigned*)(sHs + lb*264 + kt2*32 + half*16 + 4*q);
          dst[0] = d0; dst[1] = d1;
        }
    }
  }
  __syncthreads();

  // ---- GEMM2 once per bin: out[bin] = W2^T @ hsum[bin] + cnt*b2 ----
  {
    const int mt2 = wave;   // 8 waves x 16 feats = 128 feats
    f32x4 acc = {0.f, 0.f, 0.f, 0.f};
    #pragma unroll
    for (int kt2 = 0; kt2 < 8; ++kt2) {
      short8 w2 = *(const short8*)(sW2 + (mt2*8 + kt2)*512 + lane*8);
      short8 hf = *(const short8*)(sHs + c*264 + kt2*32 + 8*q);
      acc = mfma16(w2, hf, acc);
    }
    const int cntc = min(wsCnt[myblk*16 + c], CAPB);
    f32x4 res;
    #pragma unroll
    for (int r = 0; r < 4; ++r)
      res[r] = acc[r] + (float)cntc * sB2[16*mt2 + 4*q + r];
    float* op = out + ((long)myblk*16 + c)*128 + 16*mt2 + 4*q;
    *(f32x4*)op = res;
  }
}

extern "C" void kernel_launch(void* const* d_in, const int* in_sizes, int n_in,
                              void* d_out, int out_size, void* d_ws, size_t ws_size,
                              hipStream_t stream) {
  const float* x  = (const float*)d_in[0];
  const int* idxs = (const int*)d_in[1];
  // d_in[2] = n_bins scalar
  const float* W1 = (const float*)d_in[3];
  const float* b1 = (const float*)d_in[4];
  const float* W2 = (const float*)d_in[5];
  const float* b2 = (const float*)d_in[6];
  float* out = (float*)d_out;
  const int n_items = in_sizes[1];
  const int n_bins = out_size / 128;            // 4096
  const int nblocks = n_bins / 16;              // 256

  int* wsCnt = (int*)d_ws;                      // 4096 ints
  int* wsIds = (int*)d_ws + 4096;               // 4096 * CAPB ints (~6.3 MB)

  hipMemsetAsync(wsCnt, 0, (size_t)n_bins * sizeof(int), stream);
  bin_items<<<1024, 256, 0, stream>>>(idxs, wsCnt, wsIds, n_items);
  mlp_bin3<<<nblocks, 512, LDS_BYTES, stream>>>(x, W1, b1, W2, b2, wsCnt, wsIds, out);
}

// Round 6
// 438.400 us; speedup vs baseline: 1.5172x; 1.5058x over previous
//
#include <hip/hip_runtime.h>
#include <hip/hip_bf16.h>

typedef __attribute__((ext_vector_type(8))) short short8;
typedef __attribute__((ext_vector_type(4))) float f32x4;
typedef __attribute__((ext_vector_type(4))) int int4v;

#define CAPB 384   // per-bin capacity (mean 244, sigma ~15.6 -> 9 sigma)

__device__ inline unsigned short f2bf(float f) {   // RNE, used in cold paths only
  unsigned u = __float_as_uint(f);
  return (unsigned short)((u + 0x7FFFu + ((u >> 16) & 1u)) >> 16);
}
__device__ inline short bfc(float f) {             // hot path: compiler lowers to v_cvt_pk
  __hip_bfloat16 h = __float2bfloat16(f);
  return *(short*)&h;
}
__device__ inline __attribute__((always_inline))
f32x4 mfma16(short8 a, short8 b, f32x4 c) {
  return __builtin_amdgcn_mfma_f32_16x16x32_bf16(a, b, c, 0, 0, 0);
}

// ---------------- kernel A: bin items into d_ws buckets ----------------
__global__ __launch_bounds__(256)
void bin_items(const int* __restrict__ idxs, int* __restrict__ wsCnt,
               int* __restrict__ wsIds, int n_items)
{
  const int i0 = blockIdx.x * blockDim.x + threadIdx.x;
  const int stride = gridDim.x * blockDim.x;
  const int nq = n_items >> 2;
  const int4v* idx4 = (const int4v*)idxs;
  for (int s = i0; s < nq; s += stride) {
    int4v v = idx4[s];
    #pragma unroll
    for (int e = 0; e < 4; ++e) {
      int bin = v[e];
      int pos = atomicAdd(&wsCnt[bin], 1);
      if (pos < CAPB) wsIds[bin * CAPB + pos] = s * 4 + e;
    }
  }
  for (int i = (nq << 2) + i0; i < n_items; i += stride) {
    int bin = idxs[i];
    int pos = atomicAdd(&wsCnt[bin], 1);
    if (pos < CAPB) wsIds[bin * CAPB + pos] = i;
  }
}

// ---------------- kernel B: per-bin MLP h-sums + GEMM2 ----------------
// LDS: sW1 32768B | sW2 65536B | sB1 1024B | sB2 512B | sHs 8448B = 108288B
#define LDS_BYTES 108288

// waves_per_eu(2,2): LDS (108KB) already limits us to 1 block/CU = 2 waves/EU.
// Pinning it tells the allocator the true budget (512/2 = 256 VGPRs) — rounds
// 4-5 it silently targeted 4 waves/EU (128 VGPRs) and spilled ~1 GB to scratch.
__global__ __launch_bounds__(512) __attribute__((amdgpu_waves_per_eu(2, 2)))
void mlp_bin4(const float* __restrict__ x,
              const float* __restrict__ W1,
              const float* __restrict__ b1,
              const float* __restrict__ W2,
              const float* __restrict__ b2,
              const int* __restrict__ wsCnt,
              const int* __restrict__ wsIds,
              float* __restrict__ out)
{
  extern __shared__ char smem[];
  unsigned short* sW1 = (unsigned short*)smem;            // 16384
  unsigned short* sW2 = sW1 + 16384;                      // 32768
  float* sB1 = (float*)(smem + 98304);                    // 256
  float* sB2 = (float*)(smem + 99328);                    // 128
  unsigned short* sHs = (unsigned short*)(smem + 99840);  // 16*264

  const int tid = threadIdx.x;
  const int myblk = blockIdx.x;

  // ---- weight swizzle f32 -> bf16 MFMA fragments (layout verified r1-r5) ----
  for (int f = tid; f < 16384; f += 512) {
    int blk = f >> 9;                 // mt*2+kt
    int mt = blk >> 1, kt = blk & 1;
    int ln = (f >> 3) & 63, j = f & 7;
    int qq = ln >> 4, cc = ln & 15;
    sW1[f] = f2bf(W1[(32*kt + 8*qq + j)*256 + 16*mt + cc]);
  }
  for (int f = tid; f < 32768; f += 512) {
    int blk = f >> 9;                 // mt2*8+kt2
    int mt2 = blk >> 3, kt2 = blk & 7;
    int ln = (f >> 3) & 63, j = f & 7;
    int qq = ln >> 4, cc = ln & 15;
    sW2[f] = f2bf(W2[(32*kt2 + 8*qq + j)*128 + 16*mt2 + cc]);
  }
  if (tid < 256) sB1[tid] = b1[tid];
  if (tid < 128) sB2[tid] = b2[tid];
  __syncthreads();

  const int lane = tid & 63;
  const int wave = tid >> 6;
  const int c = lane & 15;
  const int q = lane >> 4;

  // ---- each wave owns 2 bins; accumulate sum of relu(W1^T x + b1) in regs ----
  #pragma unroll 1
  for (int bsel = 0; bsel < 2; ++bsel) {
    const int lb = wave * 2 + bsel;
    const int gbin = myblk * 16 + lb;
    const int cnt = min(wsCnt[gbin], CAPB);
    const int passes = (cnt + 31) >> 5;          // 32 items per pass (G=2 groups)
    const int* ids = wsIds + gbin * CAPB;

    float hsum[8][8];   // [kt2][half*4+r]
    #pragma unroll
    for (int a = 0; a < 8; ++a)
      #pragma unroll
      for (int bq = 0; bq < 8; ++bq) hsum[a][bq] = 0.f;

    f32x4 xr[8];        // raw f32 prefetch for next pass (2 groups x 4 vecs)
    short8 xf[2][2];    // current pass bf16 fragments

    // prologue: gather + convert pass 0
    if (passes > 0) {
      #pragma unroll
      for (int gi = 0; gi < 2; ++gi) {
        int slot = gi*16 + c;
        int id = ids[min(slot, cnt - 1)];
        const float* xp = x + (long)id * 64 + 8*q;
        xr[gi*4+0] = *(const f32x4*)(xp);
        xr[gi*4+1] = *(const f32x4*)(xp + 4);
        xr[gi*4+2] = *(const f32x4*)(xp + 32);
        xr[gi*4+3] = *(const f32x4*)(xp + 36);
      }
      #pragma unroll
      for (int gi = 0; gi < 2; ++gi) {
        bool v = (gi*16 + c) < cnt;
        f32x4 a0 = xr[gi*4+0], a1 = xr[gi*4+1], a2 = xr[gi*4+2], a3 = xr[gi*4+3];
        short8 f0, f1;
        f0[0]=bfc(a0[0]); f0[1]=bfc(a0[1]); f0[2]=bfc(a0[2]); f0[3]=bfc(a0[3]);
        f0[4]=bfc(a1[0]); f0[5]=bfc(a1[1]); f0[6]=bfc(a1[2]); f0[7]=bfc(a1[3]);
        f1[0]=bfc(a2[0]); f1[1]=bfc(a2[1]); f1[2]=bfc(a2[2]); f1[3]=bfc(a2[3]);
        f1[4]=bfc(a3[0]); f1[5]=bfc(a3[1]); f1[6]=bfc(a3[2]); f1[7]=bfc(a3[3]);
        short8 z = {0,0,0,0,0,0,0,0};
        xf[gi][0] = v ? f0 : z;
        xf[gi][1] = v ? f1 : z;
      }
    }

    for (int p = 0; p < passes; ++p) {
      // issue next pass's gather early (hidden under the MFMA sweep)
      if (p + 1 < passes) {
        #pragma unroll
        for (int gi = 0; gi < 2; ++gi) {
          int slot = (p+1)*32 + gi*16 + c;
          int id = ids[min(slot, cnt - 1)];
          const float* xp = x + (long)id * 64 + 8*q;
          xr[gi*4+0] = *(const f32x4*)(xp);
          xr[gi*4+1] = *(const f32x4*)(xp + 4);
          xr[gi*4+2] = *(const f32x4*)(xp + 32);
          xr[gi*4+3] = *(const f32x4*)(xp + 36);
        }
      }

      // GEMM1 sweep: 16 weight tiles x 2 item-groups, relu-accumulate
      #pragma unroll
      for (int kt2 = 0; kt2 < 8; ++kt2) {
        #pragma unroll
        for (int half = 0; half < 2; ++half) {
          const int mt = 2*kt2 + half;
          f32x4 bias = *(const f32x4*)(sB1 + 16*mt + 4*q);
          f32x4 g1v[2];
          #pragma unroll
          for (int gi = 0; gi < 2; ++gi) g1v[gi] = bias;
          short8 w0 = *(const short8*)(sW1 + (mt*2 + 0)*512 + lane*8);
          #pragma unroll
          for (int gi = 0; gi < 2; ++gi) g1v[gi] = mfma16(w0, xf[gi][0], g1v[gi]);
          short8 w1 = *(const short8*)(sW1 + (mt*2 + 1)*512 + lane*8);
          #pragma unroll
          for (int gi = 0; gi < 2; ++gi) g1v[gi] = mfma16(w1, xf[gi][1], g1v[gi]);
          #pragma unroll
          for (int gi = 0; gi < 2; ++gi)
            #pragma unroll
            for (int r = 0; r < 4; ++r)
              hsum[kt2][half*4 + r] += fmaxf(g1v[gi][r], 0.f);
        }
      }

      // convert next pass (compiler inserts waitcnt on xr here)
      if (p + 1 < passes) {
        #pragma unroll
        for (int gi = 0; gi < 2; ++gi) {
          bool v = ((p+1)*32 + gi*16 + c) < cnt;
          f32x4 a0 = xr[gi*4+0], a1 = xr[gi*4+1], a2 = xr[gi*4+2], a3 = xr[gi*4+3];
          short8 f0, f1;
          f0[0]=bfc(a0[0]); f0[1]=bfc(a0[1]); f0[2]=bfc(a0[2]); f0[3]=bfc(a0[3]);
          f0[4]=bfc(a1[0]); f0[5]=bfc(a1[1]); f0[6]=bfc(a1[2]); f0[7]=bfc(a1[3]);
          f1[0]=bfc(a2[0]); f1[1]=bfc(a2[1]); f1[2]=bfc(a2[2]); f1[3]=bfc(a2[3]);
          f1[4]=bfc(a3[0]); f1[5]=bfc(a3[1]); f1[6]=bfc(a3[2]); f1[7]=bfc(a3[3]);
          short8 z = {0,0,0,0,0,0,0,0};
          xf[gi][0] = v ? f0 : z;
          xf[gi][1] = v ? f1 : z;
        }
      }
    }

    // padded items contributed exactly relu(b1) each -> subtract (wave-uniform n)
    const int n_inv = passes*32 - cnt;
    if (n_inv > 0) {
      const float fn = (float)n_inv;
      #pragma unroll
      for (int kt2 = 0; kt2 < 8; ++kt2)
        #pragma unroll
        for (int half = 0; half < 2; ++half)
          #pragma unroll
          for (int r = 0; r < 4; ++r)
            hsum[kt2][half*4 + r] -= fn * fmaxf(sB1[16*(2*kt2+half) + 4*q + r], 0.f);
    }

    // cross-lane reduce over the 16 item-columns (lane bits 0-3)
    #pragma unroll
    for (int a = 0; a < 8; ++a)
      #pragma unroll
      for (int bq = 0; bq < 8; ++bq) {
        float v = hsum[a][bq];
        v += __shfl_xor(v, 1);
        v += __shfl_xor(v, 2);
        v += __shfl_xor(v, 4);
        v += __shfl_xor(v, 8);
        hsum[a][bq] = v;
      }

    // stage bin h-sum as bf16 (c==0 lanes; q covers the 4q+r rows)
    if (c == 0) {
      #pragma unroll
      for (int kt2 = 0; kt2 < 8; ++kt2)
        #pragma unroll
        for (int half = 0; half < 2; ++half) {
          unsigned d0 = (unsigned)f2bf(hsum[kt2][half*4+0]) | ((unsigned)f2bf(hsum[kt2][half*4+1]) << 16);
          unsigned d1 = (unsigned)f2bf(hsum[kt2][half*4+2]) | ((unsigned)f2bf(hsum[kt2][half*4+3]) << 16);
          unsigned* dst = (unsigned*)(sHs + lb*264 + kt2*32 + half*16 + 4*q);
          dst[0] = d0; dst[1] = d1;
        }
    }
  }
  __syncthreads();

  // ---- GEMM2 once per bin: out[bin] = W2^T @ hsum[bin] + cnt*b2 ----
  {
    const int mt2 = wave;   // 8 waves x 16 feats = 128 feats
    f32x4 acc = {0.f, 0.f, 0.f, 0.f};
    #pragma unroll
    for (int kt2 = 0; kt2 < 8; ++kt2) {
      short8 w2 = *(const short8*)(sW2 + (mt2*8 + kt2)*512 + lane*8);
      short8 hf = *(const short8*)(sHs + c*264 + kt2*32 + 8*q);
      acc = mfma16(w2, hf, acc);
    }
    const int cntc = min(wsCnt[myblk*16 + c], CAPB);
    f32x4 res;
    #pragma unroll
    for (int r = 0; r < 4; ++r)
      res[r] = acc[r] + (float)cntc * sB2[16*mt2 + 4*q + r];
    float* op = out + ((long)myblk*16 + c)*128 + 16*mt2 + 4*q;
    *(f32x4*)op = res;
  }
}

extern "C" void kernel_launch(void* const* d_in, const int* in_sizes, int n_in,
                              void* d_out, int out_size, void* d_ws, size_t ws_size,
                              hipStream_t stream) {
  const float* x  = (const float*)d_in[0];
  const int* idxs = (const int*)d_in[1];
  // d_in[2] = n_bins scalar
  const float* W1 = (const float*)d_in[3];
  const float* b1 = (const float*)d_in[4];
  const float* W2 = (const float*)d_in[5];
  const float* b2 = (const float*)d_in[6];
  float* out = (float*)d_out;
  const int n_items = in_sizes[1];
  const int n_bins = out_size / 128;            // 4096
  const int nblocks = n_bins / 16;              // 256

  int* wsCnt = (int*)d_ws;                      // 4096 ints
  int* wsIds = (int*)d_ws + 4096;               // 4096 * CAPB ints (~6.3 MB)

  hipMemsetAsync(wsCnt, 0, (size_t)n_bins * sizeof(int), stream);
  bin_items<<<1024, 256, 0, stream>>>(idxs, wsCnt, wsIds, n_items);
  mlp_bin4<<<nblocks, 512, LDS_BYTES, stream>>>(x, W1, b1, W2, b2, wsCnt, wsIds, out);
}

// Round 7
// 167.699 us; speedup vs baseline: 3.9662x; 2.6142x over previous
//
#include <hip/hip_runtime.h>
#include <hip/hip_bf16.h>

typedef __attribute__((ext_vector_type(8))) short short8;
typedef __attribute__((ext_vector_type(4))) float f32x4;
typedef __attribute__((ext_vector_type(4))) int int4v;

#define CAPB 384   // per-bin capacity (mean 244, sigma ~15.6 -> 9 sigma)

__device__ inline unsigned short f2bf(float f) {   // RNE, cold paths only
  unsigned u = __float_as_uint(f);
  return (unsigned short)((u + 0x7FFFu + ((u >> 16) & 1u)) >> 16);
}
__device__ inline short bfc(float f) {             // hot path: v_cvt via compiler
  __hip_bfloat16 h = __float2bfloat16(f);
  return *(short*)&h;
}
__device__ inline __attribute__((always_inline))
f32x4 mfma16(short8 a, short8 b, f32x4 c) {
  return __builtin_amdgcn_mfma_f32_16x16x32_bf16(a, b, c, 0, 0, 0);
}
// async global->LDS, 16B per lane. Global addr per-lane; LDS dest = uniform base + lane*16.
__device__ __forceinline__ void gload_lds16(const float* g, void* l) {
  __builtin_amdgcn_global_load_lds(
      (const __attribute__((address_space(1))) void*)g,
      (__attribute__((address_space(3))) void*)l, 16, 0, 0);
}

// ---------------- kernel A: bin items into d_ws buckets ----------------
__global__ __launch_bounds__(256)
void bin_items(const int* __restrict__ idxs, int* __restrict__ wsCnt,
               int* __restrict__ wsIds, int n_items)
{
  const int i0 = blockIdx.x * blockDim.x + threadIdx.x;
  const int stride = gridDim.x * blockDim.x;
  const int nq = n_items >> 2;
  const int4v* idx4 = (const int4v*)idxs;
  for (int s = i0; s < nq; s += stride) {
    int4v v = idx4[s];
    #pragma unroll
    for (int e = 0; e < 4; ++e) {
      int bin = v[e];
      int pos = atomicAdd(&wsCnt[bin], 1);
      if (pos < CAPB) wsIds[bin * CAPB + pos] = s * 4 + e;
    }
  }
  for (int i = (nq << 2) + i0; i < n_items; i += stride) {
    int bin = idxs[i];
    int pos = atomicAdd(&wsCnt[bin], 1);
    if (pos < CAPB) wsIds[bin * CAPB + pos] = i;
  }
}

// ---------------- kernel B ----------------
// LDS map (bytes):
//   [0,      32768)  sW1    : W1^T bf16 fragments
//   [32768,  98304)  sStage : MAIN LOOP: 8 waves * (2 bufs * 4096B) x-row staging
//                    EPILOGUE (after barrier): sW2 fragments (32768 ushort)
//   [98304,  99328)  sB1
//   [99328,  99840)  sB2
//   [99840, 108288)  sHs    : 16 bins * 264 ushort
//   [108288,120576)  sIds   : 8 waves * 384 ints (bin id cache)
#define LDS_BYTES 120576

__global__ __launch_bounds__(512)
void mlp_bin5(const float* __restrict__ x,
              const float* __restrict__ W1,
              const float* __restrict__ b1,
              const float* __restrict__ W2,
              const float* __restrict__ b2,
              const int* __restrict__ wsCnt,
              const int* __restrict__ wsIds,
              float* __restrict__ out)
{
  extern __shared__ char smem[];
  unsigned short* sW1 = (unsigned short*)smem;            // 16384
  char*           sStage = smem + 32768;                  // 64 KB (main loop)
  unsigned short* sW2 = (unsigned short*)(smem + 32768);  // epilogue alias
  float* sB1 = (float*)(smem + 98304);
  float* sB2 = (float*)(smem + 99328);
  unsigned short* sHs = (unsigned short*)(smem + 99840);
  int*   sIds = (int*)(smem + 108288);

  const int tid = threadIdx.x;
  const int myblk = blockIdx.x;

  // ---- W1 -> bf16 fragments (layout verified r1-r6); W2 deferred to epilogue ----
  for (int f = tid; f < 16384; f += 512) {
    int blk = f >> 9;                 // mt*2+kt
    int mt = blk >> 1, kt = blk & 1;
    int ln = (f >> 3) & 63, j = f & 7;
    int qq = ln >> 4, cc = ln & 15;
    sW1[f] = f2bf(W1[(32*kt + 8*qq + j)*256 + 16*mt + cc]);
  }
  if (tid < 256) sB1[tid] = b1[tid];
  if (tid < 128) sB2[tid] = b2[tid];
  __syncthreads();

  const int lane = tid & 63;
  const int wave = tid >> 6;
  const int c = lane & 15;
  const int q = lane >> 4;
  char* myStage = sStage + wave * 8192;
  int*  myIds   = sIds + wave * 384;

  // issue one pass's gather: 4 insts, inst i -> LDS rows i*4..i*4+3 (linear dest).
  // Source chunk XOR-swizzled so read-back (stride-256B rows) is bank-conflict-free.
  auto issue = [&](int pp, int bb, int cnt) {
    char* dst = myStage + bb * 4096;
    #pragma unroll
    for (int i = 0; i < 4; ++i) {
      int r = i*4 + (lane >> 4);
      int slot = pp*16 + r;
      int id = myIds[min(slot, cnt - 1)];
      int ch = (lane & 15) ^ (r & 7);
      gload_lds16(x + (long)id * 64 + ch * 4, dst + i * 1024);
    }
  };

  #pragma unroll 1
  for (int bsel = 0; bsel < 2; ++bsel) {
    const int lb = wave * 2 + bsel;
    const int gbin = myblk * 16 + lb;
    const int cnt = min(wsCnt[gbin], CAPB);
    const int passes = (cnt + 15) >> 4;          // 16 items per pass
    const int* idsG = wsIds + gbin * CAPB;

    // cache this bin's ids in LDS
    for (int j = lane; j < cnt; j += 64) myIds[j] = idsG[j];
    asm volatile("s_waitcnt vmcnt(0)" ::: "memory");   // drain before counted waits

    float hsum[8][8];
    #pragma unroll
    for (int a = 0; a < 8; ++a)
      #pragma unroll
      for (int bq = 0; bq < 8; ++bq) hsum[a][bq] = 0.f;

    if (passes > 0) issue(0, 0, cnt);

    for (int p = 0; p < passes; ++p) {
      if (p + 1 < passes) {
        issue(p + 1, (p + 1) & 1, cnt);
        asm volatile("s_waitcnt vmcnt(4)" ::: "memory");  // pass p done; p+1 in flight
      } else {
        asm volatile("s_waitcnt vmcnt(0)" ::: "memory");
      }
      const char* buf = myStage + (p & 1) * 4096;

      // read row c (item column), cols 8q..8q+7 per kt; un-swizzle chunks
      f32x4 v00 = *(const f32x4*)(buf + c*256 + (((2*q + 0)) ^ (c & 7))*16);
      f32x4 v01 = *(const f32x4*)(buf + c*256 + (((2*q + 1)) ^ (c & 7))*16);
      f32x4 v10 = *(const f32x4*)(buf + c*256 + (((8 + 2*q + 0)) ^ (c & 7))*16);
      f32x4 v11 = *(const f32x4*)(buf + c*256 + (((8 + 2*q + 1)) ^ (c & 7))*16);
      short8 xf0, xf1;
      xf0[0]=bfc(v00[0]); xf0[1]=bfc(v00[1]); xf0[2]=bfc(v00[2]); xf0[3]=bfc(v00[3]);
      xf0[4]=bfc(v01[0]); xf0[5]=bfc(v01[1]); xf0[6]=bfc(v01[2]); xf0[7]=bfc(v01[3]);
      xf1[0]=bfc(v10[0]); xf1[1]=bfc(v10[1]); xf1[2]=bfc(v10[2]); xf1[3]=bfc(v10[3]);
      xf1[4]=bfc(v11[0]); xf1[5]=bfc(v11[1]); xf1[6]=bfc(v11[2]); xf1[7]=bfc(v11[3]);
      const bool valid = (p*16 + c) < cnt;
      short8 z = {0,0,0,0,0,0,0,0};
      xf0 = valid ? xf0 : z;
      xf1 = valid ? xf1 : z;

      // GEMM1 sweep: 16 weight tiles, relu-accumulate into hsum
      #pragma unroll
      for (int kt2 = 0; kt2 < 8; ++kt2) {
        #pragma unroll
        for (int half = 0; half < 2; ++half) {
          const int mt = 2*kt2 + half;
          f32x4 g1 = *(const f32x4*)(sB1 + 16*mt + 4*q);
          short8 w0 = *(const short8*)(sW1 + (mt*2 + 0)*512 + lane*8);
          g1 = mfma16(w0, xf0, g1);
          short8 w1 = *(const short8*)(sW1 + (mt*2 + 1)*512 + lane*8);
          g1 = mfma16(w1, xf1, g1);
          #pragma unroll
          for (int r = 0; r < 4; ++r)
            hsum[kt2][half*4 + r] += fmaxf(g1[r], 0.f);
        }
      }
    }

    // padded items contributed exactly relu(b1) each -> subtract
    const int n_inv = passes*16 - cnt;
    if (n_inv > 0) {
      const float fn = (float)n_inv;
      #pragma unroll
      for (int kt2 = 0; kt2 < 8; ++kt2)
        #pragma unroll
        for (int half = 0; half < 2; ++half)
          #pragma unroll
          for (int r = 0; r < 4; ++r)
            hsum[kt2][half*4 + r] -= fn * fmaxf(sB1[16*(2*kt2+half) + 4*q + r], 0.f);
    }

    // cross-lane reduce over 16 item-columns
    #pragma unroll
    for (int a = 0; a < 8; ++a)
      #pragma unroll
      for (int bq = 0; bq < 8; ++bq) {
        float v = hsum[a][bq];
        v += __shfl_xor(v, 1);
        v += __shfl_xor(v, 2);
        v += __shfl_xor(v, 4);
        v += __shfl_xor(v, 8);
        hsum[a][bq] = v;
      }

    // stage bin h-sum as bf16
    if (c == 0) {
      #pragma unroll
      for (int kt2 = 0; kt2 < 8; ++kt2)
        #pragma unroll
        for (int half = 0; half < 2; ++half) {
          unsigned d0 = (unsigned)f2bf(hsum[kt2][half*4+0]) | ((unsigned)f2bf(hsum[kt2][half*4+1]) << 16);
          unsigned d1 = (unsigned)f2bf(hsum[kt2][half*4+2]) | ((unsigned)f2bf(hsum[kt2][half*4+3]) << 16);
          unsigned* dst = (unsigned*)(sHs + lb*264 + kt2*32 + half*16 + 4*q);
          dst[0] = d0; dst[1] = d1;
        }
    }
  }
  __syncthreads();   // all staging traffic done -> safe to overwrite with sW2

  // ---- build W2 fragments in the (former) staging region ----
  for (int f = tid; f < 32768; f += 512) {
    int blk = f >> 9;                 // mt2*8+kt2
    int mt2 = blk >> 3, kt2 = blk & 7;
    int ln = (f >> 3) & 63, j = f & 7;
    int qq = ln >> 4, cc = ln & 15;
    sW2[f] = f2bf(W2[(32*kt2 + 8*qq + j)*128 + 16*mt2 + cc]);
  }
  __syncthreads();

  // ---- GEMM2 once per bin: out[bin] = W2^T @ hsum[bin] + cnt*b2 ----
  {
    const int mt2 = wave;   // 8 waves x 16 feats = 128 feats
    f32x4 acc = {0.f, 0.f, 0.f, 0.f};
    #pragma unroll
    for (int kt2 = 0; kt2 < 8; ++kt2) {
      short8 w2 = *(const short8*)(sW2 + (mt2*8 + kt2)*512 + lane*8);
      short8 hf = *(const short8*)(sHs + c*264 + kt2*32 + 8*q);
      acc = mfma16(w2, hf, acc);
    }
    const int cntc = min(wsCnt[myblk*16 + c], CAPB);
    f32x4 res;
    #pragma unroll
    for (int r = 0; r < 4; ++r)
      res[r] = acc[r] + (float)cntc * sB2[16*mt2 + 4*q + r];
    float* op = out + ((long)myblk*16 + c)*128 + 16*mt2 + 4*q;
    *(f32x4*)op = res;
  }
}

extern "C" void kernel_launch(void* const* d_in, const int* in_sizes, int n_in,
                              void* d_out, int out_size, void* d_ws, size_t ws_size,
                              hipStream_t stream) {
  const float* x  = (const float*)d_in[0];
  const int* idxs = (const int*)d_in[1];
  // d_in[2] = n_bins scalar
  const float* W1 = (const float*)d_in[3];
  const float* b1 = (const float*)d_in[4];
  const float* W2 = (const float*)d_in[5];
  const float* b2 = (const float*)d_in[6];
  float* out = (float*)d_out;
  const int n_items = in_sizes[1];
  const int n_bins = out_size / 128;            // 4096
  const int nblocks = n_bins / 16;              // 256

  int* wsCnt = (int*)d_ws;                      // 4096 ints
  int* wsIds = (int*)d_ws + 4096;               // 4096 * CAPB ints (~6.3 MB)

  hipMemsetAsync(wsCnt, 0, (size_t)n_bins * sizeof(int), stream);
  bin_items<<<1024, 256, 0, stream>>>(idxs, wsCnt, wsIds, n_items);
  mlp_bin5<<<nblocks, 512, LDS_BYTES, stream>>>(x, W1, b1, W2, b2, wsCnt, wsIds, out);
}